// Round 1
// baseline (657.772 us; speedup 1.0000x reference)
//
#include <hip/hip_runtime.h>
#include <math.h>

#define BB 4
#define HH 8
#define NN 2048
#define DD 64
#define KTOP 16

// ---------------------------------------------------------------------------
// Kernel 1: batched GEMM over concatenated-head K dim (H*D = 512).
// L[b,i,j] = (1/64) * sum_{h,d} q[b,h,i,d] * k[b,h,j,d]
// 64x64 block tile, 256 threads (16x16), each computes 4x4.
// LDS is k-major (As[d][m], Bs[d][n]) so compute-phase frag reads are
// ds_read_b128; stride 68 floats keeps 16B alignment (68*4=272=16*17).
// Per-head chunk accumulators (accH) reduce fp32 summation error ~3x.
// ---------------------------------------------------------------------------
__global__ __launch_bounds__(256) void gemm_logits(const float* __restrict__ q,
                                                   const float* __restrict__ k,
                                                   float* __restrict__ L) {
    const int b  = blockIdx.z;
    const int i0 = blockIdx.y * 64;
    const int j0 = blockIdx.x * 64;
    const int tid = threadIdx.x;
    const int tx = tid & 15;   // output col group (4 cols)
    const int ty = tid >> 4;   // output row group (4 rows)

    __shared__ __align__(16) float As[64][68];
    __shared__ __align__(16) float Bs[64][68];

    float accT[4][4];
#pragma unroll
    for (int r = 0; r < 4; ++r)
#pragma unroll
        for (int c = 0; c < 4; ++c) accT[r][c] = 0.0f;

    for (int h = 0; h < HH; ++h) {
        const float* qbase = q + ((size_t)(b * HH + h) * NN + i0) * DD;
        const float* kbase = k + ((size_t)(b * HH + h) * NN + j0) * DD;
        // stage 64x64 A and B tiles, transposed into k-major LDS
#pragma unroll
        for (int it = 0; it < 4; ++it) {
            int flat = it * 256 + tid;     // 0..1023
            int row  = flat >> 4;          // tile row 0..63
            int c4   = (flat & 15) << 2;   // d offset 0,4,...,60
            float4 av = *(const float4*)(qbase + row * DD + c4);
            float4 bv = *(const float4*)(kbase + row * DD + c4);
            As[c4 + 0][row] = av.x; As[c4 + 1][row] = av.y;
            As[c4 + 2][row] = av.z; As[c4 + 3][row] = av.w;
            Bs[c4 + 0][row] = bv.x; Bs[c4 + 1][row] = bv.y;
            Bs[c4 + 2][row] = bv.z; Bs[c4 + 3][row] = bv.w;
        }
        __syncthreads();

        float accH[4][4];
#pragma unroll
        for (int r = 0; r < 4; ++r)
#pragma unroll
            for (int c = 0; c < 4; ++c) accH[r][c] = 0.0f;

#pragma unroll 8
        for (int kk = 0; kk < 64; ++kk) {
            float a[4], bb[4];
            *(float4*)a  = *(const float4*)(&As[kk][ty * 4]);
            *(float4*)bb = *(const float4*)(&Bs[kk][tx * 4]);
#pragma unroll
            for (int r = 0; r < 4; ++r)
#pragma unroll
                for (int c = 0; c < 4; ++c)
                    accH[r][c] = fmaf(a[r], bb[c], accH[r][c]);
        }
#pragma unroll
        for (int r = 0; r < 4; ++r)
#pragma unroll
            for (int c = 0; c < 4; ++c) accT[r][c] += accH[r][c];
        __syncthreads();
    }

    // epilogue: scale by 1/64 (exact pow2) and store fp32 logits
#pragma unroll
    for (int r = 0; r < 4; ++r) {
        int i = i0 + ty * 4 + r;
        float4 ov;
        ov.x = accT[r][0] * 0.015625f;
        ov.y = accT[r][1] * 0.015625f;
        ov.z = accT[r][2] * 0.015625f;
        ov.w = accT[r][3] * 0.015625f;
        *(float4*)(L + ((size_t)b * NN + i) * NN + j0 + tx * 4) = ov;
    }
}

// ---------------------------------------------------------------------------
// Kernel 2: per-row z = L + gumbel_f64(u); find 16th-largest z (double);
// mask = (z >= thresh). One block (256 thr) per row; values register-resident,
// 16 rounds of block-argmax via wave shuffle + 4-slot LDS combine.
// ---------------------------------------------------------------------------
__global__ __launch_bounds__(256) void topk_mask(const float* __restrict__ L,
                                                 const float* __restrict__ u,
                                                 float* __restrict__ out) {
    const int row = blockIdx.x;           // b*N + i
    const int tid = threadIdx.x;
    const float* Lrow = L + (size_t)row * NN;
    const float* urow = u + (size_t)row * NN;

    double z[8];
    bool alive[8];
#pragma unroll
    for (int j = 0; j < 8; ++j) {
        int idx = tid + j * 256;
        double uu = (double)urow[idx] + 1e-9;
        double g = -log(-log(uu) + 1e-9);
        z[j] = (double)Lrow[idx] + g;
        alive[j] = true;
    }

    __shared__ double wval[KTOP * 4];
    __shared__ int    widx[KTOP * 4];
    const int wave = tid >> 6;
    const int lane = tid & 63;

    double thresh = 0.0;
    for (int it = 0; it < KTOP; ++it) {
        // local argmax over this thread's alive elements
        double m = -1.0e300;
        int mi = -1;
#pragma unroll
        for (int j = 0; j < 8; ++j) {
            if (alive[j] && z[j] > m) { m = z[j]; mi = tid + j * 256; }
        }
        // wave argmax (64 lanes); tie -> smaller index (deterministic)
#pragma unroll
        for (int off = 32; off >= 1; off >>= 1) {
            double om = __shfl_down(m, off, 64);
            int    oi = __shfl_down(mi, off, 64);
            if (om > m || (om == m && oi != -1 && (mi == -1 || oi < mi))) {
                m = om; mi = oi;
            }
        }
        if (lane == 0) { wval[it * 4 + wave] = m; widx[it * 4 + wave] = mi; }
        __syncthreads();
        // all threads combine the 4 wave winners identically
        double bm = wval[it * 4 + 0];
        int    bi = widx[it * 4 + 0];
#pragma unroll
        for (int w = 1; w < 4; ++w) {
            double om = wval[it * 4 + w];
            int    oi = widx[it * 4 + w];
            if (om > bm || (om == bm && oi < bi)) { bm = om; bi = oi; }
        }
        if (it == KTOP - 1) thresh = bm;
        // owner retires the winner (register flag; no extra barrier needed)
        if ((bi & 255) == tid) alive[bi >> 8] = false;
    }

#pragma unroll
    for (int j = 0; j < 8; ++j) {
        int idx = tid + j * 256;
        out[(size_t)row * NN + idx] = (z[j] >= thresh) ? 1.0f : 0.0f;
    }
}

extern "C" void kernel_launch(void* const* d_in, const int* in_sizes, int n_in,
                              void* d_out, int out_size, void* d_ws, size_t ws_size,
                              hipStream_t stream) {
    const float* q = (const float*)d_in[0];
    const float* k = (const float*)d_in[1];
    const float* u = (const float*)d_in[2];
    float* out = (float*)d_out;
    float* L = (float*)d_ws;   // 8192*2048*4 B = 64 MiB of scratch

    dim3 grid1(NN / 64, NN / 64, BB);
    gemm_logits<<<grid1, 256, 0, stream>>>(q, k, L);

    topk_mask<<<BB * NN, 256, 0, stream>>>(L, u, out);
}

// Round 2
// 367.826 us; speedup vs baseline: 1.7883x; 1.7883x over previous
//
#include <hip/hip_runtime.h>
#include <math.h>

#define BB 4
#define HH 8
#define NN 2048
#define DD 64
#define KTOP 16
#define CUT_MARGIN 1e-3f

// ---------------------------------------------------------------------------
// Kernel 1: batched fp32 GEMM, K = H*D = 512 (8 head-chunks of 64).
// 128x128 block tile, 256 threads, 8x8 micro-tile as 2x2 quads of 4x4 at
// offsets {0,64}. LDS k-major with XOR swizzle (no padding):
//   As[d][m] stored at  d*128 + (m ^ (((d>>3)&7)<<2))
// -> staging writes and fragment reads are all <=2-way bank conflicts (free).
// Per-head sub-accumulators (accH) keep round-1 fp32 summation accuracy.
// ---------------------------------------------------------------------------
__global__ __launch_bounds__(256, 2) void gemm_logits(const float* __restrict__ q,
                                                      const float* __restrict__ k,
                                                      float* __restrict__ L) {
    const int b  = blockIdx.z;
    const int i0 = blockIdx.y * 128;
    const int j0 = blockIdx.x * 128;
    const int tid = threadIdx.x;
    const int tx4 = (tid & 15) * 4;   // output col group
    const int ty4 = (tid >> 4) * 4;   // output row group

    __shared__ __align__(16) float As[64 * 128];
    __shared__ __align__(16) float Bs[64 * 128];

    float accT[2][2][4][4];
#pragma unroll
    for (int qr = 0; qr < 2; ++qr)
#pragma unroll
        for (int qc = 0; qc < 2; ++qc)
#pragma unroll
            for (int r = 0; r < 4; ++r)
#pragma unroll
                for (int c = 0; c < 4; ++c) accT[qr][qc][r][c] = 0.0f;

    for (int h = 0; h < HH; ++h) {
        const float* qbase = q + ((size_t)(b * HH + h) * NN + i0) * DD;
        const float* kbase = k + ((size_t)(b * HH + h) * NN + j0) * DD;

        __syncthreads();   // previous compute done before overwriting LDS
        // stage 128 rows x 64 d, transposed+swizzled into LDS
#pragma unroll
        for (int it = 0; it < 8; ++it) {
            const int flat = it * 256 + tid;
            const int row  = flat >> 4;          // 0..127
            const int d4   = (flat & 15) << 2;   // 0,4,...,60
            // ((d4+e)>>3)&7 is independent of e -> one swizzle per load
            const int sw   = row ^ ((((flat & 15) >> 1) & 7) << 2);
            float qa[4], ka[4];
            *(float4*)qa = *(const float4*)(qbase + row * DD + d4);
            *(float4*)ka = *(const float4*)(kbase + row * DD + d4);
#pragma unroll
            for (int e = 0; e < 4; ++e) {
                As[(d4 + e) * 128 + sw] = qa[e];
                Bs[(d4 + e) * 128 + sw] = ka[e];
            }
        }
        __syncthreads();

        float accH[2][2][4][4];
#pragma unroll
        for (int qr = 0; qr < 2; ++qr)
#pragma unroll
            for (int qc = 0; qc < 2; ++qc)
#pragma unroll
                for (int r = 0; r < 4; ++r)
#pragma unroll
                    for (int c = 0; c < 4; ++c) accH[qr][qc][r][c] = 0.0f;

#pragma unroll 8
        for (int kk = 0; kk < 64; ++kk) {
            const int P = ((kk >> 3) & 7) << 2;   // loop-invariant per unroll-8 group
            const float* Ab = &As[kk * 128];
            const float* Bb = &Bs[kk * 128];
            float a[2][4], bf[2][4];
            *(float4*)a[0]  = *(const float4*)(Ab + (ty4 ^ P));
            *(float4*)a[1]  = *(const float4*)(Ab + 64 + (ty4 ^ P));
            *(float4*)bf[0] = *(const float4*)(Bb + (tx4 ^ P));
            *(float4*)bf[1] = *(const float4*)(Bb + 64 + (tx4 ^ P));
#pragma unroll
            for (int qr = 0; qr < 2; ++qr)
#pragma unroll
                for (int r = 0; r < 4; ++r)
#pragma unroll
                    for (int qc = 0; qc < 2; ++qc)
#pragma unroll
                        for (int c = 0; c < 4; ++c)
                            accH[qr][qc][r][c] =
                                fmaf(a[qr][r], bf[qc][c], accH[qr][qc][r][c]);
        }
#pragma unroll
        for (int qr = 0; qr < 2; ++qr)
#pragma unroll
            for (int qc = 0; qc < 2; ++qc)
#pragma unroll
                for (int r = 0; r < 4; ++r)
#pragma unroll
                    for (int c = 0; c < 4; ++c) accT[qr][qc][r][c] += accH[qr][qc][r][c];
    }

    const float s = 0.015625f;   // 1/64 exact
#pragma unroll
    for (int qr = 0; qr < 2; ++qr)
#pragma unroll
        for (int r = 0; r < 4; ++r) {
            const int i = i0 + qr * 64 + (ty4 >> 2) * 4 + r;   // i0 + qr*64 + ty*4 + r
            float* Lp = L + ((size_t)b * NN + i) * NN + j0;
#pragma unroll
            for (int qc = 0; qc < 2; ++qc) {
                float4 ov;
                ov.x = accT[qr][qc][r][0] * s;
                ov.y = accT[qr][qc][r][1] * s;
                ov.z = accT[qr][qc][r][2] * s;
                ov.w = accT[qr][qc][r][3] * s;
                *(float4*)(Lp + qc * 64 + tx4) = ov;
            }
        }
}

// ---------------------------------------------------------------------------
// Kernel 2: per-row top-16 threshold + mask, f32 prefilter + f64 refine.
// ---------------------------------------------------------------------------
__device__ __forceinline__ unsigned long long flip64(double x) {
    unsigned long long v = (unsigned long long)__double_as_longlong(x);
    return v ^ ((0ULL - (v >> 63)) | 0x8000000000000000ULL);
}
__device__ __forceinline__ double unflip64(unsigned long long k) {
    unsigned long long v = (k >> 63) ? (k ^ 0x8000000000000000ULL) : ~k;
    return __longlong_as_double((long long)v);
}

__global__ __launch_bounds__(256, 4) void topk_mask(const float* __restrict__ L,
                                                    const float* __restrict__ u,
                                                    float* __restrict__ out) {
    const int row = blockIdx.x;           // b*N + i
    const int tid = threadIdx.x;
    const float* Lrow = L + (size_t)row * NN;
    const float* urow = u + (size_t)row * NN;
    float* orow = out + (size_t)row * NN;

    __shared__ float s_tmax[256];
    __shared__ float s_cutoff;
    __shared__ int   s_cnt;
    __shared__ int   s_clist[64];

    if (tid == 0) s_cnt = 0;

    // ---- phase 0: vectorized loads, f32 z, zero the output row -------------
    float Lr[8], ur[8];
    *(float4*)&Lr[0] = *(const float4*)(Lrow + tid * 8);
    *(float4*)&Lr[4] = *(const float4*)(Lrow + tid * 8 + 4);
    *(float4*)&ur[0] = *(const float4*)(urow + tid * 8);
    *(float4*)&ur[4] = *(const float4*)(urow + tid * 8 + 4);

    float z32[8];
#pragma unroll
    for (int j = 0; j < 8; ++j) {
        // -log(-log(u+1e-9)+1e-9) via log1p for relative accuracy near u->1
        float v = (ur[j] - 1.0f) + 1e-9f;
        float w = -log1pf(v);              // = -log(u + 1e-9), w >= 0
        float g = -__logf(w + 1e-9f);
        z32[j] = Lr[j] + g;
    }
    float4 zero4 = make_float4(0.f, 0.f, 0.f, 0.f);
    *(float4*)(orow + tid * 8)     = zero4;
    *(float4*)(orow + tid * 8 + 4) = zero4;

    float tm = z32[0];
#pragma unroll
    for (int j = 1; j < 8; ++j) tm = fmaxf(tm, z32[j]);
    s_tmax[tid] = tm;
    __syncthreads();

    // ---- phase 1 (wave 0): 16th largest of 64 group-maxima = lower bound ---
    if (tid < 64) {
        float v = fmaxf(fmaxf(s_tmax[tid], s_tmax[tid + 64]),
                        fmaxf(s_tmax[tid + 128], s_tmax[tid + 192]));
        // bitonic sort ascending across 64 lanes (21 compare-exchange steps)
#pragma unroll
        for (int kS = 2; kS <= 64; kS <<= 1) {
#pragma unroll
            for (int j = kS >> 1; j > 0; j >>= 1) {
                float o = __shfl_xor(v, j, 64);
                bool asc = ((tid & kS) == 0);
                bool lower = ((tid & j) == 0);
                float mn = fminf(v, o), mx = fmaxf(v, o);
                v = (asc == lower) ? mn : mx;
            }
        }
        float K = __shfl(v, 48, 64);       // 16th largest group-max <= z32_(16)
        if (tid == 0) s_cutoff = K - CUT_MARGIN;
    }
    __syncthreads();

    // ---- phase 2: candidate scan (all threads) ------------------------------
    const float cut = s_cutoff;
#pragma unroll
    for (int j = 0; j < 8; ++j) {
        if (z32[j] >= cut) {
            int slot = atomicAdd(&s_cnt, 1);
            if (slot < 64) s_clist[slot] = tid * 8 + j;
        }
    }
    __syncthreads();

    // ---- phase 3 (wave 0): f64 refine, (c-15)-th smallest, scatter mask ----
    if (tid < 64) {
        int c = s_cnt; if (c > 64) c = 64;
        unsigned long long key = 0xFFFFFFFFFFFFFFFFULL;
        double z64 = 0.0;
        int myidx = -1;
        if (tid < c) {
            myidx = s_clist[tid];
            double uu = (double)urow[myidx] + 1e-9;
            double w  = -log(uu);
            double g  = -log(w + 1e-9);
            z64 = (double)Lrow[myidx] + g;
            key = flip64(z64);
        }
        const int rounds = c - (KTOP - 1);   // >=1 since c>=16
        unsigned long long m = 0;
        for (int r = 0; r < rounds; ++r) {
            m = key;
#pragma unroll
            for (int off = 32; off >= 1; off >>= 1) {
                unsigned long long o = __shfl_xor(m, off, 64);
                m = (o < m) ? o : m;
            }
            unsigned long long bmask = __ballot(key == m);
            int first = __builtin_ctzll(bmask);
            if (tid == first) key = 0xFFFFFFFFFFFFFFFFULL;   // retire exactly one
        }
        double thresh = unflip64(m);         // true 16th-largest z64
        if (myidx >= 0) orow[myidx] = (z64 >= thresh) ? 1.0f : 0.0f;
    }
}

extern "C" void kernel_launch(void* const* d_in, const int* in_sizes, int n_in,
                              void* d_out, int out_size, void* d_ws, size_t ws_size,
                              hipStream_t stream) {
    const float* q = (const float*)d_in[0];
    const float* k = (const float*)d_in[1];
    const float* u = (const float*)d_in[2];
    float* out = (float*)d_out;
    float* L = (float*)d_ws;   // 8192*2048*4 B = 64 MiB scratch

    dim3 grid1(NN / 128, NN / 128, BB);
    gemm_logits<<<grid1, 256, 0, stream>>>(q, k, L);

    topk_mask<<<BB * NN, 256, 0, stream>>>(L, u, out);
}

// Round 3
// 231.023 us; speedup vs baseline: 2.8472x; 1.5922x over previous
//
#include <hip/hip_runtime.h>
#include <math.h>

#define BB 4
#define HH 8
#define NN 2048
#define DD 64
#define KTOP 16
#define CUT_MARGIN 1e-3f

typedef _Float16 half_t;
typedef __attribute__((ext_vector_type(8))) _Float16 half8;
typedef __attribute__((ext_vector_type(4))) _Float16 half4v;
typedef __attribute__((ext_vector_type(4))) float floatx4;

// ---------------------------------------------------------------------------
// Kernel 0: split fp32 q,k into f16 hi + f16 (lo * 2048).
// a = hi + lo*2^-11 exactly to f16 precision of the residual (~2^-22 rel).
// lo scaled by 2^11 so it stays in f16 normal range (no denormal-flush risk
// in the MFMA); compensated at the GEMM epilogue.
// ---------------------------------------------------------------------------
__global__ __launch_bounds__(256) void split_f16(const float* __restrict__ q,
                                                 const float* __restrict__ kk,
                                                 half_t* __restrict__ qhi,
                                                 half_t* __restrict__ qlo,
                                                 half_t* __restrict__ khi,
                                                 half_t* __restrict__ klo) {
    const int NQ4 = BB * HH * NN * DD / 4;   // 1M float4 units per tensor
    int gid = blockIdx.x * 256 + threadIdx.x;
    const float* src; half_t* dhi; half_t* dlo; int i4;
    if (gid < NQ4) { src = q;  dhi = qhi; dlo = qlo; i4 = gid; }
    else           { src = kk; dhi = khi; dlo = klo; i4 = gid - NQ4; }
    float4 x = ((const float4*)src)[i4];
    float xs[4] = {x.x, x.y, x.z, x.w};
    half4v h, l;
#pragma unroll
    for (int e = 0; e < 4; ++e) {
        half_t hi = (half_t)xs[e];
        float  r  = xs[e] - (float)hi;
        h[e] = hi;
        l[e] = (half_t)(r * 2048.0f);
    }
    *(half4v*)(dhi + (size_t)i4 * 4) = h;
    *(half4v*)(dlo + (size_t)i4 * 4) = l;
}

// ---------------------------------------------------------------------------
// Kernel 1: L = (1/64) * sum_{h,d} q.k via f16x3 MFMA (16x16x32_f16).
// 128x128 block tile, 4 waves in 2x2, each wave 4x4 tiles of 16x16.
// acc1 = hi.hi ; acc2 = hi.lo' + lo'.hi (scaled 2^11); L = (acc1 + acc2/2048)/64.
// LDS: 4 arrays of 128x64 f16 (64 KB exactly), XOR-swizzled 16B units
// (unit kg ^ (row&7)) -> <=2-way bank conflicts on staging and frag reads.
// Writes L into d_out (top-k converts it to the mask in place).
// ---------------------------------------------------------------------------
__global__ __launch_bounds__(256, 2) void gemm_f16x3(const half_t* __restrict__ qhi,
                                                     const half_t* __restrict__ qlo,
                                                     const half_t* __restrict__ khi,
                                                     const half_t* __restrict__ klo,
                                                     float* __restrict__ L) {
    const int b  = blockIdx.z;
    const int i0 = blockIdx.y * 128;
    const int j0 = blockIdx.x * 128;
    const int tid  = threadIdx.x;
    const int wave = tid >> 6, lane = tid & 63;
    const int wr = wave >> 1, wc = wave & 1;
    const int lm = lane & 15, quad = lane >> 4;

    __shared__ __align__(16) half_t Ah[128 * 64];
    __shared__ __align__(16) half_t Al[128 * 64];
    __shared__ __align__(16) half_t Bh[128 * 64];
    __shared__ __align__(16) half_t Bl[128 * 64];

    floatx4 acc1[4][4], acc2[4][4];
#pragma unroll
    for (int tr = 0; tr < 4; ++tr)
#pragma unroll
        for (int tc = 0; tc < 4; ++tc) {
            acc1[tr][tc] = (floatx4)0.0f;
            acc2[tr][tc] = (floatx4)0.0f;
        }

    for (int h = 0; h < HH; ++h) {
        const size_t aoff = ((size_t)(b * HH + h) * NN + i0) * DD;
        const size_t boff = ((size_t)(b * HH + h) * NN + j0) * DD;
        __syncthreads();
#pragma unroll
        for (int it = 0; it < 4; ++it) {
            const int u   = it * 256 + tid;   // 0..1023 16B-units
            const int row = u >> 3;           // 0..127
            const int kg  = u & 7;            // 16B unit within row
            const int lidx = row * 64 + ((kg ^ (row & 7)) << 3);
            const size_t ga = aoff + row * DD + kg * 8;
            const size_t gb = boff + row * DD + kg * 8;
            *(half8*)&Ah[lidx] = *(const half8*)&qhi[ga];
            *(half8*)&Al[lidx] = *(const half8*)&qlo[ga];
            *(half8*)&Bh[lidx] = *(const half8*)&khi[gb];
            *(half8*)&Bl[lidx] = *(const half8*)&klo[gb];
        }
        __syncthreads();

#pragma unroll
        for (int ks = 0; ks < 2; ++ks) {
            half8 ah[4], al[4], bh[4], bl[4];
            const int unit = ks * 4 + quad;   // 16B unit index in k
#pragma unroll
            for (int t = 0; t < 4; ++t) {
                const int am = wr * 64 + t * 16 + lm;
                const int bm = wc * 64 + t * 16 + lm;
                const int ai = am * 64 + ((unit ^ (am & 7)) << 3);
                const int bi = bm * 64 + ((unit ^ (bm & 7)) << 3);
                ah[t] = *(const half8*)&Ah[ai];
                al[t] = *(const half8*)&Al[ai];
                bh[t] = *(const half8*)&Bh[bi];
                bl[t] = *(const half8*)&Bl[bi];
            }
#pragma unroll
            for (int tr = 0; tr < 4; ++tr)
#pragma unroll
                for (int tc = 0; tc < 4; ++tc) {
                    acc1[tr][tc] = __builtin_amdgcn_mfma_f32_16x16x32_f16(
                        ah[tr], bh[tc], acc1[tr][tc], 0, 0, 0);
                    acc2[tr][tc] = __builtin_amdgcn_mfma_f32_16x16x32_f16(
                        ah[tr], bl[tc], acc2[tr][tc], 0, 0, 0);
                    acc2[tr][tc] = __builtin_amdgcn_mfma_f32_16x16x32_f16(
                        al[tr], bh[tc], acc2[tr][tc], 0, 0, 0);
                }
        }
    }

    const float s1 = 0.015625f;            // 1/64
    const float s2 = 0.015625f / 2048.0f;  // undo lo scaling
#pragma unroll
    for (int tr = 0; tr < 4; ++tr)
#pragma unroll
        for (int r = 0; r < 4; ++r) {
            const int grow = i0 + wr * 64 + tr * 16 + quad * 4 + r;
            float* Lp = L + ((size_t)b * NN + grow) * NN + j0 + wc * 64 + lm;
#pragma unroll
            for (int tc = 0; tc < 4; ++tc)
                Lp[tc * 16] = acc1[tr][tc][r] * s1 + acc2[tr][tc][r] * s2;
        }
}

// ---------------------------------------------------------------------------
// Kernel 2: one wave per row. z32 prefilter -> cutoff (16th of 64 lane-maxima
// via bitonic, minus margin) -> ballot-prefix candidate gather (save L to LDS)
// -> zero row -> f64 refine (min-retire to 16th largest) -> scatter ones.
// LM = d_out, read (logits) then overwritten (mask) in place.
// ---------------------------------------------------------------------------
__device__ __forceinline__ unsigned long long flip64(double x) {
    unsigned long long v = (unsigned long long)__double_as_longlong(x);
    return v ^ ((0ULL - (v >> 63)) | 0x8000000000000000ULL);
}
__device__ __forceinline__ double unflip64(unsigned long long k) {
    unsigned long long v = (k >> 63) ? (k ^ 0x8000000000000000ULL) : ~k;
    return __longlong_as_double((long long)v);
}

__global__ __launch_bounds__(256, 3) void topk_mask(float* LM,   // no restrict: in-place
                                                    const float* __restrict__ u) {
    const int wave = threadIdx.x >> 6, lane = threadIdx.x & 63;
    const int row = blockIdx.x * 4 + wave;
    float* lrow = LM + (size_t)row * NN;
    const float* urow = u + (size_t)row * NN;

    __shared__ int   s_idx[4][64];
    __shared__ float s_L[4][64];

    // phase 0: load row, compute z32
    float Lv[32], z[32];
#pragma unroll
    for (int e = 0; e < 8; ++e) {
        float4 lv = *(const float4*)(lrow + e * 256 + lane * 4);
        float4 uv = *(const float4*)(urow + e * 256 + lane * 4);
        float ls[4] = {lv.x, lv.y, lv.z, lv.w};
        float us[4] = {uv.x, uv.y, uv.z, uv.w};
#pragma unroll
        for (int s = 0; s < 4; ++s) {
            float v = (us[s] - 1.0f) + 1e-9f;
            float w = -log1pf(v);            // = -log(u+1e-9), accurate near u->1
            float g = -__logf(w + 1e-9f);
            Lv[e * 4 + s] = ls[s];
            z[e * 4 + s]  = ls[s] + g;
        }
    }

    // phase 1: cutoff = (16th largest of 64 lane-maxima) - margin
    float v = z[0];
#pragma unroll
    for (int r = 1; r < 32; ++r) v = fmaxf(v, z[r]);
#pragma unroll
    for (int kS = 2; kS <= 64; kS <<= 1) {
#pragma unroll
        for (int j = kS >> 1; j > 0; j >>= 1) {
            float o = __shfl_xor(v, j, 64);
            bool asc = ((lane & kS) == 0);
            bool lower = ((lane & j) == 0);
            float mn = fminf(v, o), mx = fmaxf(v, o);
            v = (asc == lower) ? mn : mx;
        }
    }
    const float cut = __shfl(v, 48, 64) - CUT_MARGIN;

    // phase 2: ballot-prefix candidate gather; then zero the row
    int c = 0;
#pragma unroll
    for (int r = 0; r < 32; ++r) {
        bool p = (z[r] >= cut);
        unsigned long long m = __ballot(p);
        if (p) {
            int slot = c + __popcll(m & ((1ULL << lane) - 1ULL));
            if (slot < 64) {
                s_idx[wave][slot] = (r >> 2) * 256 + lane * 4 + (r & 3);
                s_L[wave][slot]   = Lv[r];
            }
        }
        c += __popcll(m);
    }
    if (c > 64) c = 64;

    float4 z4 = make_float4(0.f, 0.f, 0.f, 0.f);
#pragma unroll
    for (int e = 0; e < 8; ++e)
        *(float4*)(lrow + e * 256 + lane * 4) = z4;
    __syncthreads();   // drains vmcnt: zero-stores complete before scatter

    // phase 3: f64 refine on candidates, threshold = 16th largest z64
    unsigned long long key = 0xFFFFFFFFFFFFFFFFULL;
    double z64 = 0.0;
    int myidx = -1;
    if (lane < c) {
        myidx = s_idx[wave][lane];
        double uu = (double)urow[myidx] + 1e-9;
        double w  = -log(uu);
        double g  = -log(w + 1e-9);
        z64 = (double)s_L[wave][lane] + g;
        key = flip64(z64);
    }
    const int rounds = c - (KTOP - 1);   // >=1 since c>=16 by construction
    unsigned long long m = 0;
    for (int r = 0; r < rounds; ++r) {
        m = key;
#pragma unroll
        for (int off = 32; off >= 1; off >>= 1) {
            unsigned long long o = __shfl_xor(m, off, 64);
            m = (o < m) ? o : m;
        }
        unsigned long long bm = __ballot(key == m);
        if (lane == __builtin_ctzll(bm)) key = 0xFFFFFFFFFFFFFFFFULL;
    }
    double thresh = unflip64(m);
    if (myidx >= 0) lrow[myidx] = (z64 >= thresh) ? 1.0f : 0.0f;
}

extern "C" void kernel_launch(void* const* d_in, const int* in_sizes, int n_in,
                              void* d_out, int out_size, void* d_ws, size_t ws_size,
                              hipStream_t stream) {
    const float* q = (const float*)d_in[0];
    const float* k = (const float*)d_in[1];
    const float* u = (const float*)d_in[2];
    float* out = (float*)d_out;          // logits scratch, then final mask
    const size_t NQ = (size_t)BB * HH * NN * DD;   // 4M elements
    half_t* qhi = (half_t*)d_ws;
    half_t* qlo = qhi + NQ;
    half_t* khi = qlo + NQ;
    half_t* klo = khi + NQ;              // 32 MB total in d_ws

    split_f16<<<(2 * NQ / 4) / 256, 256, 0, stream>>>(q, k, qhi, qlo, khi, klo);

    dim3 grid1(NN / 128, NN / 128, BB);
    gemm_f16x3<<<grid1, 256, 0, stream>>>(qhi, qlo, khi, klo, out);

    topk_mask<<<(BB * NN) / 4, 256, 0, stream>>>(out, u);
}